// Round 5
// baseline (830.669 us; speedup 1.0000x reference)
//
#include <hip/hip_runtime.h>
#include <cfloat>

#define B_TOTAL 131072
#define N_CB    1024
#define DIM     64
#define DEPTH   4
#define BM      128     // rows per block (4 waves x 32)
#define RS      68      // res row stride (floats)
#define EPS     0.075f  // band: covers bf16-split coarse err + 13-bit key truncation

typedef __bf16 bf16x8 __attribute__((ext_vector_type(8)));
typedef unsigned short u16x8 __attribute__((ext_vector_type(8)));
typedef float f32x16 __attribute__((ext_vector_type(16)));

#define MFMA(a, b, c) __builtin_amdgcn_mfma_f32_32x32x16_bf16(a, b, c, 0, 0, 0)

static __device__ __forceinline__ unsigned umin32(unsigned a, unsigned b) { return a < b ? a : b; }
static __device__ __forceinline__ unsigned umax32(unsigned a, unsigned b) { return a > b ? a : b; }
static __device__ __forceinline__ float kf(unsigned k) {
  return __builtin_bit_cast(float, k & 0xFFFFFC00u);
}

static __device__ __forceinline__ unsigned short f2bf(float f) {
  unsigned u = __builtin_bit_cast(unsigned, f);
  return (unsigned short)((u + 0x7fffu + ((u >> 16) & 1u)) >> 16);
}
static __device__ __forceinline__ float bf2f(unsigned short h) {
  unsigned u = ((unsigned)h) << 16;
  return __builtin_bit_cast(float, u);
}

// Pre-split codebook into MFMA fragment layout (bh/bl) + fp32 norms.
// frag element: [(t*4+m)*64 + lane][j] = cb[32t + (lane&31)][16m + 8*(lane>>5) + j]
__global__ void prep_kernel(const float* __restrict__ cb,
                            unsigned short* __restrict__ bh,
                            unsigned short* __restrict__ bl,
                            float* __restrict__ c2) {
  const int t = blockIdx.x;            // 0..31
  const int l = threadIdx.x;           // 0..63
  const int tc = l & 31, hi = l >> 5;
  const int row = 32 * t + tc;
  #pragma unroll
  for (int m = 0; m < 4; ++m) {
    const float* p = cb + row * DIM + 16 * m + 8 * hi;
    const size_t o = (((size_t)t * 4 + m) * 64 + l) * 8;
    #pragma unroll
    for (int j = 0; j < 8; ++j) {
      float f = p[j];
      unsigned short h = f2bf(f);
      bh[o + j] = h;
      bl[o + j] = f2bf(f - bf2f(h));
    }
  }
  if (hi == 0) {
    const float* p = cb + row * DIM;
    float s = 0.f;
    #pragma unroll
    for (int k = 0; k < DIM; ++k) s += p[k] * p[k];
    c2[row] = s;
  }
}

// LDS: res 34816 + c2s 4096 + preds 512 = 39424 B -> 4 blocks/CU
__global__ __launch_bounds__(256, 4)
void rvq_mfma_kernel(const float* __restrict__ z,
                     const float* __restrict__ cbg,
                     const unsigned short* __restrict__ bh,
                     const unsigned short* __restrict__ bl,
                     const float* __restrict__ c2g,
                     float* __restrict__ out) {
  __shared__ __align__(16) float res[BM][RS];  // fp32 residual, per-wave 32-row panels
  __shared__ __align__(16) float c2s[N_CB];
  __shared__ int preds[BM];

  const int tid  = threadIdx.x;
  const int wave = tid >> 6;
  const int l    = tid & 63;
  const int tc   = l & 31;
  const int hi   = l >> 5;
  const int wr   = wave * 32;
  const int row0 = blockIdx.x * BM;

  float* zq   = out;
  float* maps = out + (size_t)B_TOTAL * DIM;

  // ---- stage z -> res (coalesced), c2 -> LDS ----
  {
    const float4* z4 = (const float4*)(z + (size_t)row0 * DIM);
    #pragma unroll
    for (int i = 0; i < 8; ++i) {
      const int f = i * 256 + tid;
      float4 v = z4[f];
      const int r = (f * 4) >> 6, d0 = (f * 4) & 63;
      *(float4*)&res[r][d0] = v;
    }
    for (int i = tid; i < N_CB; i += 256) c2s[i] = c2g[i];
  }
  __syncthreads();

  for (int depth = 0; depth < DEPTH; ++depth) {
    // ---- residual (B-operand) fragments, split bf16, + exact row norm ----
    bf16x8 Rh[4], Rl[4];
    float zp = 0.f;
    {
      const int arow = wr + tc;
      #pragma unroll
      for (int m = 0; m < 4; ++m) {
        u16x8 uh, ul;
        #pragma unroll
        for (int jj = 0; jj < 8; ++jj) {
          const float f = res[arow][16 * m + 8 * hi + jj];
          zp += f * f;
          const unsigned short h = f2bf(f);
          uh[jj] = h;
          ul[jj] = f2bf(f - bf2f(h));
        }
        Rh[m] = __builtin_bit_cast(bf16x8, uh);
        Rl[m] = __builtin_bit_cast(bf16x8, ul);
      }
    }
    const float z2 = zp + __shfl_xor(zp, 32);  // both lane halves get full norm

    // packed top-3 keys for THIS lane's row (wr+tc): (dist_bits & ~1023) | col
    unsigned m1 = 0xFFFFFFFFu, m2 = 0xFFFFFFFFu, m3 = 0xFFFFFFFFu;

    float* mrow = maps + ((size_t)depth * B_TOTAL + row0 + wr + tc) * N_CB + 4 * hi;
    const float4* c2p = (const float4*)c2s;

    #pragma unroll 2
    for (int t = 0; t < 32; ++t) {
      const bf16x8* ap = (const bf16x8*)bh + (size_t)(t * 4) * 64 + l;
      const bf16x8* lp = (const bf16x8*)bl + (size_t)(t * 4) * 64 + l;
      const bf16x8 A0 = ap[0], A1 = ap[64], A2 = ap[128], A3 = ap[192];
      const bf16x8 L0 = lp[0], L1 = lp[64], L2 = lp[128], L3 = lp[192];

      f32x16 acc;
      #pragma unroll
      for (int s = 0; s < 16; ++s) acc[s] = 0.f;
      acc = MFMA(A0, Rh[0], acc);
      acc = MFMA(A1, Rh[1], acc);
      acc = MFMA(A2, Rh[2], acc);
      acc = MFMA(A3, Rh[3], acc);
      acc = MFMA(A0, Rl[0], acc);
      acc = MFMA(A1, Rl[1], acc);
      acc = MFMA(A2, Rl[2], acc);
      acc = MFMA(A3, Rl[3], acc);
      acc = MFMA(L0, Rh[0], acc);
      acc = MFMA(L1, Rh[1], acc);
      acc = MFMA(L2, Rh[2], acc);
      acc = MFMA(L3, Rh[3], acc);

      // epilogue: acc[4q+r] = dot(cb[32t+8q+4hi+r], res-row tc)
      #pragma unroll
      for (int q = 0; q < 4; ++q) {
        const float4 c2v = c2p[8 * t + 2 * q + hi];
        float4 dv;
        dv.x = fmaf(-2.f, acc[4 * q + 0], z2 + c2v.x);
        dv.y = fmaf(-2.f, acc[4 * q + 1], z2 + c2v.y);
        dv.z = fmaf(-2.f, acc[4 * q + 2], z2 + c2v.z);
        dv.w = fmaf(-2.f, acc[4 * q + 3], z2 + c2v.w);
        *(float4*)&mrow[32 * t + 8 * q] = dv;
        const unsigned cb0 = (unsigned)(32 * t + 8 * q + 4 * hi);
        #pragma unroll
        for (int r = 0; r < 4; ++r) {
          const float dd = r == 0 ? dv.x : r == 1 ? dv.y : r == 2 ? dv.z : dv.w;
          const float dc = fmaxf(dd, 0.f);
          const unsigned k = (__builtin_bit_cast(unsigned, dc) & 0xFFFFFC00u) | (cb0 + r);
          const unsigned t2 = umax32(m1, k);
          m1 = umin32(m1, k);
          const unsigned t3 = umax32(m2, t2);
          m2 = umin32(m2, t2);
          m3 = umin32(m3, t3);
        }
      }
    }

    // ---- merge the two lanes (tc, tc+32) owning this row: top-3 of 6 ----
    const unsigned o1 = (unsigned)__shfl_xor((int)m1, 32);
    const unsigned o2 = (unsigned)__shfl_xor((int)m2, 32);
    const unsigned o3 = (unsigned)__shfl_xor((int)m3, 32);
    const unsigned x1 = umin32(m1, o1), y1 = umax32(m1, o1);
    const unsigned x2 = umin32(m2, o2);
    const unsigned x3 = umin32(m3, o3);
    const unsigned g1 = x1;
    const unsigned g2 = umin32(y1, x2);
    const unsigned g3 = umin32(umax32(x2, y1), x3);

    const float d1f = kf(g1);
    const bool amb = (kf(g2) <= d1f + EPS);
    if (hi == 0) preds[wr + tc] = (int)(g1 & 1023u);   // default decision

    // ---- rare exact fp64 refine, one ambiguous row at a time (wave-uniform) ----
    unsigned ambm = (unsigned)(__ballot(amb) & 0xffffffffull);
    while (ambm) {
      const int r = __ffs(ambm) - 1;
      ambm &= ambm - 1;
      const unsigned k1 = (unsigned)__shfl((int)g1, r);
      const unsigned k2 = (unsigned)__shfl((int)g2, r);
      const unsigned k3 = (unsigned)__shfl((int)g3, r);
      const float thr = kf(k1) + EPS;
      const double rv = (double)res[wr + r][l];
      double best = DBL_MAX;
      int bix = 0x7fffffff;
      {
        const int c = (int)(k1 & 1023u);
        double df = rv - (double)cbg[(size_t)c * DIM + l];
        double dp = df * df;
        #pragma unroll
        for (int msk = 1; msk < 64; msk <<= 1) dp += __shfl_xor(dp, msk);
        best = dp; bix = c;
      }
      if (kf(k2) <= thr) {
        const int c = (int)(k2 & 1023u);
        double df = rv - (double)cbg[(size_t)c * DIM + l];
        double dp = df * df;
        #pragma unroll
        for (int msk = 1; msk < 64; msk <<= 1) dp += __shfl_xor(dp, msk);
        if (dp < best || (dp == best && c < bix)) { best = dp; bix = c; }
      }
      if (kf(k3) <= thr) {
        const int c = (int)(k3 & 1023u);
        double df = rv - (double)cbg[(size_t)c * DIM + l];
        double dp = df * df;
        #pragma unroll
        for (int msk = 1; msk < 64; msk <<= 1) dp += __shfl_xor(dp, msk);
        if (dp < best || (dp == best && c < bix)) { best = dp; bix = c; }
      }
      if (l == 0) preds[wr + r] = bix;
    }

    // ---- residual -= codebook[pred] (fp32 elementwise, bitwise = ref) ----
    {
      const int urow = wr + tc;
      const int p = preds[urow];
      const float4* crow = (const float4*)(cbg + (size_t)p * DIM + 32 * hi);
      #pragma unroll
      for (int q = 0; q < 8; ++q) {
        const float4 cv = crow[q];
        float4* rp = (float4*)&res[urow][32 * hi + 4 * q];
        float4 rv = *rp;
        rv.x -= cv.x; rv.y -= cv.y; rv.z -= cv.z; rv.w -= cv.w;
        *rp = rv;
      }
    }
    // no __syncthreads: all depth-loop state is wave-private
  }

  __syncthreads();   // final epilogue reads the whole panel across waves

  // ---- z_q = z - residual_final ----
  {
    const float4* z4 = (const float4*)(z + (size_t)row0 * DIM);
    float4* o4 = (float4*)(zq + (size_t)row0 * DIM);
    #pragma unroll
    for (int i = 0; i < 8; ++i) {
      const int f = i * 256 + tid;
      float4 v = z4[f];
      const int r = (f * 4) >> 6, d0 = (f * 4) & 63;
      const float4 rv = *(const float4*)&res[r][d0];
      v.x -= rv.x; v.y -= rv.y; v.z -= rv.z; v.w -= rv.w;
      o4[f] = v;
    }
  }
}

extern "C" void kernel_launch(void* const* d_in, const int* in_sizes, int n_in,
                              void* d_out, int out_size, void* d_ws, size_t ws_size,
                              hipStream_t stream) {
  const float* z  = (const float*)d_in[0];
  const float* cb = (const float*)d_in[1];
  float* out = (float*)d_out;

  unsigned short* bh = (unsigned short*)d_ws;          // 65536 u16 = 128KB
  unsigned short* bl = bh + 65536;                     // 128KB
  float*          c2 = (float*)(bl + 65536);           // 4KB

  hipLaunchKernelGGL(prep_kernel, dim3(32), dim3(64), 0, stream, cb, bh, bl, c2);
  hipLaunchKernelGGL(rvq_mfma_kernel, dim3(B_TOTAL / BM), dim3(256), 0, stream,
                     z, cb, bh, bl, c2, out);
}